// Round 11
// baseline (46.715 us; speedup 1.0000x reference)
//
#include <hip/hip_runtime.h>
#include <math.h>

#define EP 65536
#define C 97
#define L 8
#define WAVES 4
#define ITERS 8                          // segments per wave
#define SEG_PER_BLOCK (WAVES * ITERS)    // 32
#define NBLOCKS (EP / SEG_PER_BLOCK)     // 2048
#define SEG_FLOATS (L * C)               // 776 floats, contiguous, 16B-aligned

typedef float f4 __attribute__((ext_vector_type(4)));
#define NT(p) __builtin_nontemporal_load(p)

// one DPP add step on the VALU pipe (not LDS)
template <int CTRL, int RMASK>
__device__ __forceinline__ float dpp_step(float v) {
    return v + __int_as_float(__builtin_amdgcn_update_dpp(
                   0, __float_as_int(v), CTRL, RMASK, 0xf, true));
}
// wave-64 sum of two values via DPP (rocPRIM pattern), chains interleaved
__device__ __forceinline__ void dpp_wsum2(float& a, float& b) {
    a = dpp_step<0x128, 0xf>(a); b = dpp_step<0x128, 0xf>(b);  // row_ror:8
    a = dpp_step<0x124, 0xf>(a); b = dpp_step<0x124, 0xf>(b);  // row_ror:4
    a = dpp_step<0x122, 0xf>(a); b = dpp_step<0x122, 0xf>(b);  // row_ror:2
    a = dpp_step<0x121, 0xf>(a); b = dpp_step<0x121, 0xf>(b);  // row_ror:1
    a = dpp_step<0x142, 0xa>(a); b = dpp_step<0x142, 0xa>(b);  // row_bcast15
    a = dpp_step<0x143, 0xc>(a); b = dpp_step<0x143, 0xc>(b);  // row_bcast31
    a = __int_as_float(__builtin_amdgcn_readlane(__float_as_int(a), 63));
    b = __int_as_float(__builtin_amdgcn_readlane(__float_as_int(b), 63));
}
__device__ __forceinline__ float dpp_wsum(float v) {
    v = dpp_step<0x128, 0xf>(v);
    v = dpp_step<0x124, 0xf>(v);
    v = dpp_step<0x122, 0xf>(v);
    v = dpp_step<0x121, 0xf>(v);
    v = dpp_step<0x142, 0xa>(v);
    v = dpp_step<0x143, 0xc>(v);
    return __int_as_float(__builtin_amdgcn_readlane(__float_as_int(v), 63));
}

// Timed replays are L3-resident (229MB < 256MB Infinity Cache; R4/R5 replay
// rows show hbm_bytes ~ 0) -> the binding constraint is LATENCY, not HBM BW.
// Depth-2 register pipeline: two buffers; at iter k we stage buf(k%2) to the
// wave-private LDS slice and immediately reissue that buffer with segment
// k+2's loads (in-flight window ~2 iterations ~ 700cy > L3 latency).
// Labels -> bitmasks and thresholds -> SGPRs in a prologue burst, so the
// steady-state loop issues only the 4 wide logits loads. No fences/atomics
// (R4/R5), no scalar logits loads (R9), staging kept in LDS (R9).
__global__ __launch_bounds__(256) void atloss_main(
        const float* __restrict__ logits,
        const float* __restrict__ labels,
        const int*   __restrict__ pos,
        float*       __restrict__ partials) {
    const int tid  = threadIdx.x;
    const int w    = tid >> 6;
    const int lane = tid & 63;
    const int jbase = blockIdx.x * SEG_PER_BLOCK + w * ITERS;

    __shared__ float s_log[WAVES * SEG_FLOATS];   // 12416 B
    __shared__ float s_loss[WAVES];
    float* seg_s = s_log + w * SEG_FLOATS;        // wave-private slice
    f4*    s4    = (f4*)seg_s;                    // 3104 % 16 == 0

    const int  c0   = lane;
    const int  c1   = lane + 64;
    const bool has1 = (c1 < C);                   // 97 = 64 + 33

    // span starts -> SGPRs
    int st_l = 0;
    if (lane < ITERS) st_l = pos[2 * (jbase + lane)];
    int st_s[ITERS];
#pragma unroll
    for (int k = 0; k < ITERS; ++k)
        st_s[k] = __builtin_amdgcn_readlane(st_l, k);

    // prologue burst: labels -> 2 bitmasks (labels[:,0] forced 0: lane>0)
    unsigned pm0 = 0, pm1 = 0;
#pragma unroll
    for (int k = 0; k < ITERS; ++k) {
        const size_t lb = (size_t)(jbase + k) * C;
        const float l0 = NT(labels + lb + c0);
        const float l1 = has1 ? NT(labels + lb + c1) : 0.0f;
        pm0 |= ((lane > 0) && (l0 > 0.5f)) ? (1u << k) : 0u;
        pm1 |= (has1 && (l1 > 0.5f)) ? (1u << k) : 0u;
    }
    // raw threshold logits (wave-uniform) -> SGPRs
    float eth_s[ITERS];
#pragma unroll
    for (int k = 0; k < ITERS; ++k)
        eth_s[k] = __int_as_float(__builtin_amdgcn_readfirstlane(
            __float_as_int(logits[(size_t)(jbase + k) * C])));

    // ---- depth-2 prefetch: segments 0 and 1 in flight ----
    f4 A0, A1, A2, A3 = (f4){0.f, 0.f, 0.f, 0.f};
    f4 B0, B1, B2, B3 = (f4){0.f, 0.f, 0.f, 0.f};
    {
        const f4* ga = (const f4*)(logits + (size_t)st_s[0] * C);
        A0 = NT(ga + lane); A1 = NT(ga + lane + 64); A2 = NT(ga + lane + 128);
        if (lane < 2) A3 = NT(ga + 192 + lane);
        const f4* gb = (const f4*)(logits + (size_t)st_s[1] * C);
        B0 = NT(gb + lane); B1 = NT(gb + lane + 64); B2 = NT(gb + lane + 128);
        if (lane < 2) B3 = NT(gb + 192 + lane);
    }

    float acc_uni = 0.0f, acc_spos = 0.0f;

    // stage buf -> LDS, reissue buf with segment IT+2, compute iter IT
#define PROCESS(R0, R1, R2, R3, IT)                                          \
    {                                                                        \
        s4[lane] = R0; s4[lane + 64] = R1; s4[lane + 128] = R2;              \
        if (lane < 2) s4[192 + lane] = R3;                                   \
        if ((IT) + 2 < ITERS) {                                              \
            const f4* gn = (const f4*)(logits + (size_t)st_s[(IT) + 2] * C); \
            R0 = NT(gn + lane); R1 = NT(gn + lane + 64);                     \
            R2 = NT(gn + lane + 128);                                        \
            if (lane < 2) R3 = NT(gn + 192 + lane);                          \
        }                                                                    \
        const float eth = eth_s[(IT)];                                       \
        float e0, e1 = -INFINITY;                                            \
        {                                                                    \
            const float m01 = fmaxf(seg_s[0 * C + c0], seg_s[1 * C + c0]);   \
            const float m23 = fmaxf(seg_s[2 * C + c0], seg_s[3 * C + c0]);   \
            const float m45 = fmaxf(seg_s[4 * C + c0], seg_s[5 * C + c0]);   \
            const float m67 = fmaxf(seg_s[6 * C + c0], seg_s[7 * C + c0]);   \
            e0 = fmaxf(fmaxf(m01, m23), fmaxf(m45, m67));                    \
        }                                                                    \
        if (has1) {                                                          \
            const float m01 = fmaxf(seg_s[0 * C + c1], seg_s[1 * C + c1]);   \
            const float m23 = fmaxf(seg_s[2 * C + c1], seg_s[3 * C + c1]);   \
            const float m45 = fmaxf(seg_s[4 * C + c1], seg_s[5 * C + c1]);   \
            const float m67 = fmaxf(seg_s[6 * C + c1], seg_s[7 * C + c1]);   \
            e1 = fmaxf(fmaxf(m01, m23), fmaxf(m45, m67));                    \
        }                                                                    \
        if (lane == 0) e0 = eth;                                             \
        const bool p0 = (pm0 >> (IT)) & 1u;                                  \
        const bool p1 = (pm1 >> (IT)) & 1u;                                  \
        const float npos = (float)(__popcll(__ballot(p0)) +                  \
                                   __popcll(__ballot(p1)));                  \
        const float x0 = __expf(e0);                                         \
        const float x1 = has1 ? __expf(e1) : 0.0f;                           \
        float s_all  = x0 + x1;                                              \
        float sp_pos = (p0 ? x0 : 0.0f) + (p1 ? x1 : 0.0f);                  \
        dpp_wsum2(s_all, sp_pos);                                            \
        const float sp = __expf(eth) + sp_pos;                               \
        const float sn = s_all - sp_pos;                                     \
        acc_uni  += npos * __logf(sp) + (__logf(sn) - eth);                  \
        acc_spos += (p0 ? e0 : 0.0f) + (p1 ? e1 : 0.0f);                     \
    }

    PROCESS(A0, A1, A2, A3, 0)
    PROCESS(B0, B1, B2, B3, 1)
    PROCESS(A0, A1, A2, A3, 2)
    PROCESS(B0, B1, B2, B3, 3)
    PROCESS(A0, A1, A2, A3, 4)
    PROCESS(B0, B1, B2, B3, 5)
    PROCESS(A0, A1, A2, A3, 6)
    PROCESS(B0, B1, B2, B3, 7)
#undef PROCESS

    const float wloss = acc_uni - dpp_wsum(acc_spos);

    if (lane == 0) s_loss[w] = wloss;
    __syncthreads();
    if (tid == 0) {
        partials[blockIdx.x] = s_loss[0] + s_loss[1] + s_loss[2] + s_loss[3];
    }
}

__global__ __launch_bounds__(256) void atloss_reduce(
        const float* __restrict__ partials, int n, float* __restrict__ out) {
    __shared__ double sh[256];
    double acc = 0.0;
    for (int i = threadIdx.x; i < n; i += 256) acc += (double)partials[i];
    sh[threadIdx.x] = acc;
    __syncthreads();
    for (int s = 128; s > 0; s >>= 1) {
        if (threadIdx.x < s) sh[threadIdx.x] += sh[threadIdx.x + s];
        __syncthreads();
    }
    if (threadIdx.x == 0) out[0] = (float)(sh[0] / (double)EP);
}

extern "C" void kernel_launch(void* const* d_in, const int* in_sizes, int n_in,
                              void* d_out, int out_size, void* d_ws, size_t ws_size,
                              hipStream_t stream) {
    const float* logits = (const float*)d_in[0];
    const float* labels = (const float*)d_in[1];
    const int*   pos    = (const int*)d_in[2];
    float* out      = (float*)d_out;
    float* partials = (float*)d_ws;   // 2048 floats = 8 KiB scratch

    atloss_main<<<NBLOCKS, 256, 0, stream>>>(logits, labels, pos, partials);
    atloss_reduce<<<1, 256, 0, stream>>>(partials, NBLOCKS, out);
}